// Round 5
// baseline (252.705 us; speedup 1.0000x reference)
//
#include <hip/hip_runtime.h>
#include <cstdint>
#include <cstddef>

// Problem: B=64, R=196, L=512, K=768.
// Algebra: emb = p @ q^T + q^T = (1+p) outer q ==>
//   score[b,r,j] = (1+p[b,r]) * w[b,j],  w[b,:] = q[b,:] @ V
// out[b,r,:] = (1/Z_r) * sum_j exp(c_r*wm_j - M_r) * seq_emb[b,j,:] / sqrt(768)
//
// Round-9: DELETE kprep/seqT. Six micro/structural changes all pinned at
// 233-236us; kprep (59us, 2.2x its traffic floor) existed only to write a
// 48MB bf16 transpose read back once. New chain:
//   kqp   : q raw dots + p rows (126MB stream, no LDS, VGPR-lean)
//   kw    : unchanged (nparts=1)
//   kattn : direct-from-seq fp32 staging (verified R1 form) + wactive skip
//           + T14 split-stage (loads issued before prologue/MFMA, LDS-write
//           after) so HBM/L2 latency hides under compute.
// Removes ~96MB of traffic + one serial stage. Diagnostic: if total is STILL
// ~234, the timed window is harness-fixed-cost dominated -> plateau.

typedef __attribute__((ext_vector_type(8))) short short8;
typedef __attribute__((ext_vector_type(4))) float f32x4;

__device__ __forceinline__ unsigned short f32_to_bf16(float x) {
    unsigned int u = __float_as_uint(x);
    unsigned int r = (u + 0x7FFFu + ((u >> 16) & 1u)) >> 16;  // RNE
    return (unsigned short)r;
}
__device__ __forceinline__ float bf16_to_f32(unsigned short h) {
    return __uint_as_float(((unsigned int)h) << 16);
}

#if defined(__has_builtin)
#if __has_builtin(__builtin_amdgcn_cvt_pk_bf16_f32)
#define HAVE_PK_BF16 1
#endif
#endif

__device__ __forceinline__ unsigned int pk_bf16(float a, float b) {
#ifdef HAVE_PK_BF16
    typedef __attribute__((ext_vector_type(2))) __bf16 bf16x2;
    bf16x2 v = __builtin_amdgcn_cvt_pk_bf16_f32(a, b);
    return __builtin_bit_cast(unsigned int, v);
#else
    return (unsigned int)f32_to_bf16(a) | ((unsigned int)f32_to_bf16(b) << 16);
#endif
}

// ---- kernel 1: merged q raw dots (blocks 0..8191) + p rows (8192..11327) ---
__global__ __launch_bounds__(256) void kqp(const float* __restrict__ seq,
                                           const float* __restrict__ seqW,
                                           const float* __restrict__ img,
                                           const float* __restrict__ imgW,
                                           const float* __restrict__ imgBias,
                                           float* __restrict__ qraw,
                                           float* __restrict__ pv) {
    int wv = threadIdx.x >> 6, lane = threadIdx.x & 63;
    if (blockIdx.x < 8192) {
        // q[row] = seq[row,:768] . seqW   (raw, no bias/tanh), 32768 rows
        int row = blockIdx.x * 4 + wv;
        const float4* x4 = (const float4*)(seq + (size_t)row * 768);
        const float4* w4 = (const float4*)seqW;
        float s = 0.f;
#pragma unroll
        for (int i = 0; i < 3; ++i) {
            float4 a = x4[i * 64 + lane];
            float4 c = w4[i * 64 + lane];
            s += a.x * c.x + a.y * c.y + a.z * c.z + a.w * c.w;
        }
#pragma unroll
        for (int o = 32; o; o >>= 1) s += __shfl_xor(s, o, 64);
        if (lane == 0) qraw[row] = s;
    } else {
        // p[row] = tanh(img[row,:512] . imgW + b), 12544 rows
        int row = (blockIdx.x - 8192) * 4 + wv;
        const float4* x4 = (const float4*)(img + (size_t)row * 512);
        const float4* w4 = (const float4*)imgW;
        float s = 0.f;
#pragma unroll
        for (int i = 0; i < 2; ++i) {
            float4 a = x4[i * 64 + lane];
            float4 c = w4[i * 64 + lane];
            s += a.x * c.x + a.y * c.y + a.z * c.z + a.w * c.w;
        }
#pragma unroll
        for (int o = 32; o; o >>= 1) s += __shfl_xor(s, o, 64);
        if (lane == 0) pv[row] = tanhf(s + imgBias[0]);
    }
}

// ------- kernel 2: wm[b,j] = mask ? (tanh(qraw+b) @ V[:,j]) : -1e30 --------
// grid 512: block = (b, jc of 8), 64 cols each.
__global__ __launch_bounds__(256) void kw(const float* __restrict__ qraw,
                                          const float* __restrict__ seqBias,
                                          const float* __restrict__ V,
                                          const int* __restrict__ mask,
                                          float* __restrict__ wm) {
    __shared__ __align__(16) float sq[512];
    __shared__ __align__(16) float sacc[16][16][4];
    int b = blockIdx.x >> 3, jc = blockIdx.x & 7;
    int t = threadIdx.x;
    float qb = seqBias[0];
    sq[t] = tanhf(qraw[b * 512 + t] + qb);
    sq[t + 256] = tanhf(qraw[b * 512 + t + 256] + qb);
    __syncthreads();
    int jt = t & 15, lg = t >> 4;                 // 16 col-quads x 16 l-groups
    const float4* V4 = (const float4*)V;
    int col4 = jc * 16 + jt;
    float ax = 0.f, ay = 0.f, az = 0.f, aw = 0.f;
    int lbase = lg * 32;
#pragma unroll 8
    for (int li = 0; li < 32; ++li) {
        int l = lbase + li;
        float qq = sq[l];
        float4 v = V4[(size_t)l * 128 + col4];
        ax += qq * v.x; ay += qq * v.y; az += qq * v.z; aw += qq * v.w;
    }
    sacc[lg][jt][0] = ax; sacc[lg][jt][1] = ay;
    sacc[lg][jt][2] = az; sacc[lg][jt][3] = aw;
    __syncthreads();
    if (t < 16) {
        float sx = 0.f, sy = 0.f, sz = 0.f, sw = 0.f;
#pragma unroll
        for (int g = 0; g < 16; ++g) {
            sx += sacc[g][t][0]; sy += sacc[g][t][1];
            sz += sacc[g][t][2]; sw += sacc[g][t][3];
        }
        const int* mrow = mask + b * 512 + jc * 64 + t * 4;
        float4 o;
        o.x = mrow[0] ? sx : -1e30f;
        o.y = mrow[1] ? sy : -1e30f;
        o.z = mrow[2] ? sz : -1e30f;
        o.w = mrow[3] ? sw : -1e30f;
        ((float4*)(wm + b * 512 + jc * 64))[t] = o;
    }
}

// ------- kernel 3: softmax-weights (regs) x seq fp32->bf16 staged tile -----
// Direct-from-seq (no seqT). T14 split-stage: global loads issued early into
// regs; convert+LDS-write later. Double-buffered; 1 barrier per chunk.
__global__ __launch_bounds__(256, 2) void kattn(const float* __restrict__ seq,
                                                const float* __restrict__ p,
                                                const float* __restrict__ wm,
                                                float* __restrict__ out) {
    __shared__ __align__(16) unsigned int sseq[2][128 * 32];  // 2 x 16 KB
    __shared__ __align__(16) float swm[512];
    __shared__ float sinvz[64];
    __shared__ float sred[16];

    int id = blockIdx.x;
    int rt = id & 3;
    int nt = (id >> 2) % 6;
    int b  = id / 24;
    int t  = threadIdx.x;
    int wv = t >> 6, lane = t & 63;
    int mm = lane & 15, q = lane >> 4;
    int nb = nt * 128;

    const float* seqb = seq + (size_t)b * 512 * 768 + nb;
    int tl = t & 31, jp = t >> 5;
    int n0 = tl * 4;

    float4 A0[4], A1[4];   // in-flight chunk (T14 split staging)
    auto stage_load = [&](int ch) {
#pragma unroll
        for (int pass = 0; pass < 4; ++pass) {
            int jl = pass * 16 + jp * 2;
            int jglob = ch * 64 + jl;
            A0[pass] = *(const float4*)(seqb + (size_t)jglob * 768 + n0);
            A1[pass] = *(const float4*)(seqb + (size_t)(jglob + 1) * 768 + n0);
        }
    };
    auto stage_write = [&](int buf) {
        unsigned int* sb = sseq[buf];
#pragma unroll
        for (int pass = 0; pass < 4; ++pass) {
            int jl = pass * 16 + jp * 2;
            int g = jl >> 3;
            int wo = (jl & 7) >> 1;
            float a0v[4] = {A0[pass].x, A0[pass].y, A0[pass].z, A0[pass].w};
            float a1v[4] = {A1[pass].x, A1[pass].y, A1[pass].z, A1[pass].w};
#pragma unroll
            for (int i = 0; i < 4; ++i) {
                int n = n0 + i;
                int sw = (n ^ (n >> 3)) & 7;
                sb[n * 32 + ((g ^ sw) << 2) + wo] = pk_bf16(a0v[i], a1v[i]);
            }
        }
    };

    stage_load(0);   // issue chunk-0 loads; latency hides under prologue

    float v0 = wm[b * 512 + t];
    float v1 = wm[b * 512 + t + 256];
    swm[t] = v0; swm[t + 256] = v1;
    float lmax = fmaxf(v0, v1);
    float fa = (v0 > -1e29f) ? v0 : 1e30f;
    float fb = (v1 > -1e29f) ? v1 : 1e30f;
    float lmin = fminf(fa, fb);
#pragma unroll
    for (int o = 32; o; o >>= 1) {
        lmax = fmaxf(lmax, __shfl_xor(lmax, o, 64));
        lmin = fminf(lmin, __shfl_xor(lmin, o, 64));
    }
    if (lane == 0) { sred[wv] = lmax; sred[8 + wv] = lmin; }
    __syncthreads();

    // wave-uniform: does this wave own ANY valid row (< 196)?
    bool wactive = (rt * 64 + wv * 16) < 196;
    int rl = wv * 16 + mm;
    int r  = rt * 64 + rl;
    bool valid = r < 196;

    short8 afrag[16];
    if (wactive) {
        float wmax = fmaxf(fmaxf(sred[0], sred[1]), fmaxf(sred[2], sred[3]));
        float wmin = fminf(fminf(sred[8], sred[9]), fminf(sred[10], sred[11]));
        int pidx = b * 196 + (valid ? r : 195);
        float c = 1.0f + p[pidx];
        float M = (c >= 0.f) ? c * wmax : c * wmin;

        float zsum = 0.f;
        const f32x4* swm4 = (const f32x4*)swm;
#pragma unroll
        for (int tk = 0; tk < 16; ++tk) {
            int jb = tk * 32 + q * 8;
            f32x4 w0 = swm4[jb >> 2];
            f32x4 w1 = swm4[(jb >> 2) + 1];
            short8 af;
#pragma unroll
            for (int jj = 0; jj < 8; ++jj) {
                float ww = (jj < 4) ? w0[jj] : w1[jj - 4];
                float e = valid ? __expf(c * ww - M) : 0.f;
                unsigned short h = f32_to_bf16(e);
                zsum += bf16_to_f32(h);
                af[jj] = (short)h;
            }
            afrag[tk] = af;
        }
        zsum += __shfl_xor(zsum, 16, 64);
        zsum += __shfl_xor(zsum, 32, 64);
        if (q == 0) sinvz[rl] = 1.0f / zsum;
    }

    f32x4 acc[8];
#pragma unroll
    for (int s = 0; s < 8; ++s) acc[s] = (f32x4){0.f, 0.f, 0.f, 0.f};

    stage_write(0);
    __syncthreads();
#pragma unroll
    for (int ch = 0; ch < 8; ++ch) {
        if (ch < 7) stage_load(ch + 1);     // issue next chunk's loads NOW
        if (wactive) {
            const unsigned int* cb = sseq[ch & 1];
#pragma unroll
            for (int kk = 0; kk < 2; ++kk) {
                short8 bfr[8];
#pragma unroll
                for (int s = 0; s < 8; ++s) {
                    int n = s * 16 + mm;
                    int g = kk * 4 + q;
                    int sw = (n ^ (n >> 3)) & 7;
                    bfr[s] = *(const short8*)(cb + n * 32 + ((g ^ sw) << 2));
                }
#pragma unroll
                for (int s = 0; s < 8; ++s)
                    acc[s] = __builtin_amdgcn_mfma_f32_16x16x32_bf16(
                        afrag[ch * 2 + kk], bfr[s], acc[s], 0, 0, 0);
            }
        }
        if (ch < 7) stage_write((ch + 1) & 1);  // write other buffer (no race)
        __syncthreads();
    }

    if (wactive) {
        const float invsqrtk = 0.036084391824351615f;
#pragma unroll
        for (int reg = 0; reg < 4; ++reg) {
            int row = q * 4 + reg;
            int rr = rt * 64 + wv * 16 + row;
            if (rr < 196) {
                float scale = sinvz[wv * 16 + row] * invsqrtk;
                float* op = out + (size_t)(b * 196 + rr) * 768 + nb + mm;
#pragma unroll
                for (int s = 0; s < 8; ++s)
                    op[s * 16] = acc[s][reg] * scale;
            }
        }
    }
}

extern "C" void kernel_launch(void* const* d_in, const int* in_sizes, int n_in,
                              void* d_out, int out_size, void* d_ws, size_t ws_size,
                              hipStream_t stream) {
    const float* image_emb = (const float*)d_in[0];
    const float* seq_emb   = (const float*)d_in[1];
    const int*   mask      = (const int*)d_in[2];
    const float* image_W   = (const float*)d_in[3];
    const float* image_b   = (const float*)d_in[4];
    const float* seq_W     = (const float*)d_in[5];
    const float* seq_b     = (const float*)d_in[6];
    const float* V         = (const float*)d_in[7];
    float* out = (float*)d_out;

    float* p_ws = (float*)d_ws;                            // 12544 f
    float* q_ws = (float*)((char*)d_ws + (128 << 10));     // 32768 f
    float* wm_ws = (float*)((char*)d_ws + (256 << 10));    // 32768 f

    kqp<<<dim3(11328), dim3(256), 0, stream>>>(seq_emb, seq_W,
                                               image_emb, image_W, image_b,
                                               q_ws, p_ws);
    kw<<<dim3(512), dim3(256), 0, stream>>>(q_ws, seq_b, V, mask, wm_ws);
    kattn<<<dim3(1536), dim3(256), 0, stream>>>(seq_emb, p_ws, wm_ws, out);
}

// Round 6
// 231.051 us; speedup vs baseline: 1.0937x; 1.0937x over previous
//
#include <hip/hip_runtime.h>
#include <cstdint>
#include <cstddef>

// Problem: B=64, R=196, L=512, K=768.
// Algebra: emb = p @ q^T + q^T = (1+p) outer q ==>
//   score[b,r,j] = (1+p[b,r]) * w[b,j],  w[b,:] = q[b,:] @ V
// out[b,r,:] = (1/Z_r) * sum_j exp(c_r*wm_j - M_r) * seq_emb[b,j,:] / sqrt(768)
//
// Round-10: RESTORE the Round-4 configuration (232.75us, session best).
// R5's seqT-deletion experiment regressed (+20us) but completed the
// attribution model:
//   120us = 2x 384MiB harness poison fills (write-roofline, fixed)
//   ~99us = kprep 59 + kw 10 + kattn2 30 (each at the measured ~3 TB/s
//           combined streaming ceiling; 4 independent kernel structures
//           all pin at 2.9-3.5 TB/s while write-only fills hit 6.6)
//   ~14us = dispatch gaps
// => 233us accounted. R4 chain restored verbatim:
//   kprep : seq->seqT bf16 pre-swizzled transpose + q partial slabs + p rows
//   kw    : wm = mask ? tanh(sum qpart + b) @ V : -1e30  (512 blocks)
//   kattn2: softmax-weights x seqT, global_load_lds staging, XCD-sibling
//           block mapping (rt-siblings share L2), wactive dead-wave skip

typedef __attribute__((ext_vector_type(8))) short short8;
typedef __attribute__((ext_vector_type(4))) float f32x4;

__device__ __forceinline__ unsigned short f32_to_bf16(float x) {
    unsigned int u = __float_as_uint(x);
    unsigned int r = (u + 0x7FFFu + ((u >> 16) & 1u)) >> 16;  // RNE
    return (unsigned short)r;
}
__device__ __forceinline__ float bf16_to_f32(unsigned short h) {
    return __uint_as_float(((unsigned int)h) << 16);
}

#if defined(__has_builtin)
#if __has_builtin(__builtin_amdgcn_cvt_pk_bf16_f32)
#define HAVE_PK_BF16 1
#endif
#if __has_builtin(__builtin_amdgcn_global_load_lds)
#define HAVE_GLL 1
#endif
#endif

__device__ __forceinline__ unsigned int pk_bf16(float a, float b) {
#ifdef HAVE_PK_BF16
    typedef __attribute__((ext_vector_type(2))) __bf16 bf16x2;
    bf16x2 v = __builtin_amdgcn_cvt_pk_bf16_f32(a, b);
    return __builtin_bit_cast(unsigned int, v);
#else
    return (unsigned int)f32_to_bf16(a) | ((unsigned int)f32_to_bf16(b) << 16);
#endif
}

// async 16B global->LDS copy; dest must be wave-uniform base + lane*16B.
__device__ __forceinline__ void async_ld16(const unsigned short* g,
                                           unsigned short* l) {
#ifdef HAVE_GLL
    __builtin_amdgcn_global_load_lds(
        (const __attribute__((address_space(1))) void*)g,
        (__attribute__((address_space(3))) void*)l, 16, 0, 0);
#else
    *(short8*)l = *(const short8*)g;
#endif
}

// ---- kernel 1: blocks 0..3071 transpose one 64j x 128k tile (+q partials);
//      blocks 3072..6207 compute p rows.
__global__ __launch_bounds__(256) void kprep(const float* __restrict__ seq,
                                             const float* __restrict__ seqW,
                                             const float* __restrict__ img,
                                             const float* __restrict__ imgW,
                                             const float* __restrict__ imgBias,
                                             unsigned short* __restrict__ seqT,
                                             float* __restrict__ qpart,
                                             float* __restrict__ pv) {
    __shared__ __align__(16) unsigned int sT[128 * 32];   // [k][16 j-quads x 2 u32]
    __shared__ __align__(16) float sWc[128];

    if (blockIdx.x >= 3072) {
        // ---- p[row] = tanh(image_emb[row,:512] . image_W) ----
        int wv = threadIdx.x >> 6, lane = threadIdx.x & 63;
        int row = (blockIdx.x - 3072) * 4 + wv;           // 12544 rows
        const float4* x4 = (const float4*)(img + (size_t)row * 512);
        const float4* w4 = (const float4*)imgW;
        float s = 0.f;
#pragma unroll
        for (int i = 0; i < 2; ++i) {
            float4 a = x4[i * 64 + lane];
            float4 c = w4[i * 64 + lane];
            s += a.x * c.x + a.y * c.y + a.z * c.z + a.w * c.w;
        }
#pragma unroll
        for (int o = 32; o; o >>= 1) s += __shfl_xor(s, o, 64);
        if (lane == 0) pv[row] = tanhf(s + imgBias[0]);
        return;
    }

    // ---- transpose tile: block = (b, jt, ck) ----
    int id = blockIdx.x;
    int b = id / 48, rem = id - b * 48;
    int jt = rem / 6, ck = rem - jt * 6;                  // jt = j-chunk (ch), ck = nt
    int j0 = jt * 64;
    int t = threadIdx.x;
    if (t < 128) sWc[t] = seqW[ck * 128 + t];

    int quad = t >> 4, kseg = t & 15;                     // 4 j-rows x (2x4) k
    int qk = quad ^ kseg;
    const float* base = seq + (size_t)b * 512 * 768 + (size_t)(j0 + quad * 4) * 768 + ck * 128;
    int jg = t & 7, krow = t >> 3;                        // readout: 8 cols x 32 k-rows
    float qp[4] = {0.f, 0.f, 0.f, 0.f};
    __syncthreads();

#pragma unroll
    for (int rp = 0; rp < 2; ++rp) {
        int kq = rp * 64 + kseg * 4;                      // local k 0..124
        float4 r0 = *(const float4*)(base + 0 * 768 + kq);
        float4 r1 = *(const float4*)(base + 1 * 768 + kq);
        float4 r2 = *(const float4*)(base + 2 * 768 + kq);
        float4 r3 = *(const float4*)(base + 3 * 768 + kq);
        float4 w  = *(const float4*)(sWc + kq);
        qp[0] += r0.x * w.x + r0.y * w.y + r0.z * w.z + r0.w * w.w;
        qp[1] += r1.x * w.x + r1.y * w.y + r1.z * w.z + r1.w * w.w;
        qp[2] += r2.x * w.x + r2.y * w.y + r2.z * w.z + r2.w * w.w;
        qp[3] += r3.x * w.x + r3.y * w.y + r3.z * w.z + r3.w * w.w;
        float a0[4] = {r0.x, r0.y, r0.z, r0.w};
        float a1[4] = {r1.x, r1.y, r1.z, r1.w};
        float a2[4] = {r2.x, r2.y, r2.z, r2.w};
        float a3[4] = {r3.x, r3.y, r3.z, r3.w};
#pragma unroll
        for (int i = 0; i < 4; ++i) {
            int k = kq + i;
            int col = (qk ^ (i << 2)) & 15;
            uint2 v;
            v.x = pk_bf16(a0[i], a1[i]);
            v.y = pk_bf16(a2[i], a3[i]);
            *(uint2*)(sT + k * 32 + col * 2) = v;
        }
    }
    __syncthreads();
    // store: chunk-contiguous pre-swizzled image [k 128][col 8 x 16B]
    unsigned short* dst = seqT + (((size_t)b * 6 + ck) * 8 + jt) * (128 * 64);
#pragma unroll
    for (int wp = 0; wp < 4; ++wp) {
        int k = wp * 32 + krow;
        int s = ((k >> 2) & 15) ^ ((k & 3) << 2);
        int sw = (k ^ (k >> 3)) & 7;
        int jgOut = jg ^ sw;
        int c0 = ((jgOut << 1) ^ s) & 15;
        int c1 = c0 ^ 1;
        uint2 va = *(const uint2*)(sT + k * 32 + c0 * 2);
        uint2 vb = *(const uint2*)(sT + k * 32 + c1 * 2);
        uint4 o;
        o.x = va.x; o.y = va.y; o.z = vb.x; o.w = vb.y;
        *(uint4*)(dst + (size_t)k * 64 + jg * 8) = o;     // wave: 1KB contiguous
    }
    // q partial dots -> disjoint ck slab (no atomics)
#pragma unroll
    for (int rr = 0; rr < 4; ++rr) {
        float s = qp[rr];
        s += __shfl_xor(s, 8, 64);
        s += __shfl_xor(s, 4, 64);
        s += __shfl_xor(s, 2, 64);
        s += __shfl_xor(s, 1, 64);
        if (kseg == 0)
            qpart[(size_t)ck * 32768 + b * 512 + j0 + quad * 4 + rr] = s;
    }
}

// ---------------- fallback: p rows standalone -------------------------------
__global__ __launch_bounds__(256) void krows_p(const float* __restrict__ x,
                                               const float* __restrict__ w,
                                               const float* __restrict__ bias,
                                               float* __restrict__ outp) {
    int wv = threadIdx.x >> 6, lane = threadIdx.x & 63;
    int row = blockIdx.x * 4 + wv;
    const float4* x4 = (const float4*)(x + (size_t)row * 512);
    const float4* w4 = (const float4*)w;
    float s = 0.f;
#pragma unroll
    for (int i = 0; i < 2; ++i) {
        float4 a = x4[i * 64 + lane];
        float4 c = w4[i * 64 + lane];
        s += a.x * c.x + a.y * c.y + a.z * c.z + a.w * c.w;
    }
#pragma unroll
    for (int o = 32; o; o >>= 1) s += __shfl_xor(s, o, 64);
    if (lane == 0) outp[row] = tanhf(s + bias[0]);
}

// ---------------- fallback: q rows standalone (raw dot, no bias/tanh) -------
__global__ __launch_bounds__(256) void krows_q(const float* __restrict__ x,
                                               const float* __restrict__ w,
                                               float* __restrict__ outp) {
    int wv = threadIdx.x >> 6, lane = threadIdx.x & 63;
    int row = blockIdx.x * 4 + wv;
    const float4* x4 = (const float4*)(x + (size_t)row * 768);
    const float4* w4 = (const float4*)w;
    float s = 0.f;
#pragma unroll
    for (int i = 0; i < 3; ++i) {
        float4 a = x4[i * 64 + lane];
        float4 c = w4[i * 64 + lane];
        s += a.x * c.x + a.y * c.y + a.z * c.z + a.w * c.w;
    }
#pragma unroll
    for (int o = 32; o; o >>= 1) s += __shfl_xor(s, o, 64);
    if (lane == 0) outp[row] = s;
}

// ------- kernel 3: wm[b,j] = mask ? (tanh(sum qpart+b) @ V[:,j]) : -1e30 ----
// grid 512: block = (b, jc of 8), 64 cols each; 2 blocks/CU.
__global__ __launch_bounds__(256) void kw(const float* __restrict__ qpart,
                                          const float* __restrict__ seqBias,
                                          const float* __restrict__ V,
                                          const int* __restrict__ mask,
                                          float* __restrict__ wm,
                                          int nparts) {
    __shared__ __align__(16) float sq[512];
    __shared__ __align__(16) float sacc[16][16][4];
    int b = blockIdx.x >> 3, jc = blockIdx.x & 7;
    int t = threadIdx.x;
    float qb = seqBias[0];
    float a0 = 0.f, a1 = 0.f;
    for (int pp = 0; pp < nparts; ++pp) {
        a0 += qpart[(size_t)pp * 32768 + b * 512 + t];
        a1 += qpart[(size_t)pp * 32768 + b * 512 + t + 256];
    }
    sq[t] = tanhf(a0 + qb);
    sq[t + 256] = tanhf(a1 + qb);
    __syncthreads();
    int jt = t & 15, lg = t >> 4;                 // 16 col-quads x 16 l-groups
    const float4* V4 = (const float4*)V;
    int col4 = jc * 16 + jt;
    float ax = 0.f, ay = 0.f, az = 0.f, aw = 0.f;
    int lbase = lg * 32;
#pragma unroll 8
    for (int li = 0; li < 32; ++li) {
        int l = lbase + li;
        float qq = sq[l];
        float4 v = V4[(size_t)l * 128 + col4];
        ax += qq * v.x; ay += qq * v.y; az += qq * v.z; aw += qq * v.w;
    }
    sacc[lg][jt][0] = ax; sacc[lg][jt][1] = ay;
    sacc[lg][jt][2] = az; sacc[lg][jt][3] = aw;
    __syncthreads();
    if (t < 16) {
        float sx = 0.f, sy = 0.f, sz = 0.f, sw = 0.f;
#pragma unroll
        for (int g = 0; g < 16; ++g) {
            sx += sacc[g][t][0]; sy += sacc[g][t][1];
            sz += sacc[g][t][2]; sw += sacc[g][t][3];
        }
        const int* mrow = mask + b * 512 + jc * 64 + t * 4;
        float4 o;
        o.x = mrow[0] ? sx : -1e30f;
        o.y = mrow[1] ? sy : -1e30f;
        o.z = mrow[2] ? sz : -1e30f;
        o.w = mrow[3] ? sw : -1e30f;
        ((float4*)(wm + b * 512 + jc * 64))[t] = o;
    }
}

// ------- kernel 4: softmax-weights (regs) x seqT bf16 tile (LDS) ------------
// Staging via async global_load_lds (16B), early-issued; linear layout.
__global__ __launch_bounds__(256, 2) void kattn2(const unsigned short* __restrict__ seqT,
                                                 const float* __restrict__ p,
                                                 const float* __restrict__ wm,
                                                 float* __restrict__ out) {
    __shared__ __align__(16) unsigned short sB[2][128 * 64];  // 2 x 16 KB
    __shared__ __align__(16) float swm[512];
    __shared__ float sinvz[64];
    __shared__ float sred[16];

    int raw = blockIdx.x;
    int g  = ((raw >> 5) << 3) + (raw & 7);           // 0..383 = (b,nt)
    int rt = (raw >> 3) & 3;                          // rt-siblings: same XCD
    int b  = g / 6, nt = g - b * 6;
    int t  = threadIdx.x;
    int wv = t >> 6, lane = t & 63;
    int mm = lane & 15, q = lane >> 4;
    int nb = nt * 128;

    // chunk (b,nt,ch) is 16KB contiguous, pre-swizzled: stage = linear copy
    const unsigned short* seqTb = seqT + ((size_t)(b * 6 + nt) * 8) * (128 * 64);
    int toff = t * 8;                                   // 16B per thread
    auto stage = [&](int ch, int buf) {
        const unsigned short* src = seqTb + (size_t)ch * 8192 + toff;
        unsigned short* ld = sB[buf] + toff;
#pragma unroll
        for (int pp = 0; pp < 4; ++pp)
            async_ld16(src + pp * 2048, ld + pp * 2048);
    };

    stage(0, 0);   // async issue ASAP: latency hides under softmax prologue

    float v0 = wm[b * 512 + t];
    float v1 = wm[b * 512 + t + 256];
    swm[t] = v0; swm[t + 256] = v1;
    float lmax = fmaxf(v0, v1);
    float fa = (v0 > -1e29f) ? v0 : 1e30f;
    float fb = (v1 > -1e29f) ? v1 : 1e30f;
    float lmin = fminf(fa, fb);
#pragma unroll
    for (int o = 32; o; o >>= 1) {
        lmax = fmaxf(lmax, __shfl_xor(lmax, o, 64));
        lmin = fminf(lmin, __shfl_xor(lmin, o, 64));
    }
    if (lane == 0) { sred[wv] = lmax; sred[8 + wv] = lmin; }
    __syncthreads();   // sred+swm visible; drains vmcnt -> sB[0] complete

    // wave-uniform: does this wave own ANY valid row (< 196)?
    bool wactive = (rt * 64 + wv * 16) < 196;

    int rl = wv * 16 + mm;
    int r  = rt * 64 + rl;
    bool valid = r < 196;

    short8 afrag[16];
    if (wactive) {
        float wmax = fmaxf(fmaxf(sred[0], sred[1]), fmaxf(sred[2], sred[3]));
        float wmin = fminf(fminf(sred[8], sred[9]), fminf(sred[10], sred[11]));
        int pidx = b * 196 + (valid ? r : 195);
        float c = 1.0f + p[pidx];
        float M = (c >= 0.f) ? c * wmax : c * wmin;

        float zsum = 0.f;
        const f32x4* swm4 = (const f32x4*)swm;
#pragma unroll
        for (int tk = 0; tk < 16; ++tk) {
            int jb = tk * 32 + q * 8;
            f32x4 w0 = swm4[jb >> 2];
            f32x4 w1 = swm4[(jb >> 2) + 1];
            short8 af;
#pragma unroll
            for (int jj = 0; jj < 8; ++jj) {
                float ww = (jj < 4) ? w0[jj] : w1[jj - 4];
                float e = valid ? __expf(c * ww - M) : 0.f;
                unsigned short h = f32_to_bf16(e);
                zsum += bf16_to_f32(h);
                af[jj] = (short)h;
            }
            afrag[tk] = af;
        }
        zsum += __shfl_xor(zsum, 16, 64);
        zsum += __shfl_xor(zsum, 32, 64);
        if (q == 0) sinvz[rl] = 1.0f / zsum;
    }

    f32x4 acc[8];
#pragma unroll
    for (int s = 0; s < 8; ++s) acc[s] = (f32x4){0.f, 0.f, 0.f, 0.f};

#pragma unroll
    for (int ch = 0; ch < 8; ++ch) {
        if (ch < 7) stage(ch + 1, (ch + 1) & 1);   // async prefetch next chunk
        if (wactive) {
            const unsigned short* cb = sB[ch & 1];
#pragma unroll
            for (int kk = 0; kk < 2; ++kk) {
                short8 bfr[8];
#pragma unroll
                for (int s = 0; s < 8; ++s) {
                    int n = s * 16 + mm;
                    int sw = (n ^ (n >> 3)) & 7;
                    bfr[s] = *(const short8*)(cb + n * 64 + ((((kk << 2) + q) ^ sw) << 3));
                }
#pragma unroll
                for (int s = 0; s < 8; ++s)
                    acc[s] = __builtin_amdgcn_mfma_f32_16x16x32_bf16(
                        afrag[(ch << 1) + kk], bfr[s], acc[s], 0, 0, 0);
            }
        }
        __syncthreads();   // drains prefetch vmcnt + orders LDS reuse
    }

    if (wactive) {
        const float invsqrtk = 0.036084391824351615f;
#pragma unroll
        for (int reg = 0; reg < 4; ++reg) {
            int row = q * 4 + reg;
            int rr = rt * 64 + wv * 16 + row;
            if (rr < 196) {
                float scale = sinvz[wv * 16 + row] * invsqrtk;
                float* op = out + (size_t)(b * 196 + rr) * 768 + nb + mm;
#pragma unroll
                for (int s = 0; s < 8; ++s)
                    op[s * 16] = acc[s][reg] * scale;
            }
        }
    }
}

// ------- fallback kernel 4 (fp32-source staging, round-1) -------------------
__global__ __launch_bounds__(256, 2) void kattn(const float* __restrict__ seq,
                                                const float* __restrict__ p,
                                                const float* __restrict__ wm,
                                                float* __restrict__ out) {
    __shared__ __align__(16) unsigned int sseq[2][128 * 32];
    __shared__ __align__(16) float swm[512];
    __shared__ float sinvz[64];
    __shared__ float sred[16];

    int id = blockIdx.x;
    int rt = id & 3;
    int nt = (id >> 2) % 6;
    int b  = id / 24;
    int t  = threadIdx.x;
    int wv = t >> 6, lane = t & 63;
    int mm = lane & 15, q = lane >> 4;
    int nb = nt * 128;

    float v0 = wm[b * 512 + t];
    float v1 = wm[b * 512 + t + 256];
    swm[t] = v0; swm[t + 256] = v1;
    float lmax = fmaxf(v0, v1);
    float fa = (v0 > -1e29f) ? v0 : 1e30f;
    float fb = (v1 > -1e29f) ? v1 : 1e30f;
    float lmin = fminf(fa, fb);
#pragma unroll
    for (int o = 32; o; o >>= 1) {
        lmax = fmaxf(lmax, __shfl_xor(lmax, o, 64));
        lmin = fminf(lmin, __shfl_xor(lmin, o, 64));
    }
    if (lane == 0) { sred[wv] = lmax; sred[8 + wv] = lmin; }
    __syncthreads();
    float wmax = fmaxf(fmaxf(sred[0], sred[1]), fmaxf(sred[2], sred[3]));
    float wmin = fminf(fminf(sred[8], sred[9]), fminf(sred[10], sred[11]));

    int rl = wv * 16 + mm;
    int r  = rt * 64 + rl;
    bool valid = r < 196;
    int pidx = b * 196 + (valid ? r : 195);
    float c = 1.0f + p[pidx];
    float M = (c >= 0.f) ? c * wmax : c * wmin;

    short8 afrag[16];
    float zsum = 0.f;
    const f32x4* swm4 = (const f32x4*)swm;
#pragma unroll
    for (int tk = 0; tk < 16; ++tk) {
        int jb = tk * 32 + q * 8;
        f32x4 w0 = swm4[jb >> 2];
        f32x4 w1 = swm4[(jb >> 2) + 1];
        short8 af;
#pragma unroll
        for (int jj = 0; jj < 8; ++jj) {
            float ww = (jj < 4) ? w0[jj] : w1[jj - 4];
            float e = valid ? __expf(c * ww - M) : 0.f;
            unsigned short h = f32_to_bf16(e);
            zsum += bf16_to_f32(h);
            af[jj] = (short)h;
        }
        afrag[tk] = af;
    }
    zsum += __shfl_xor(zsum, 16, 64);
    zsum += __shfl_xor(zsum, 32, 64);
    if (q == 0) sinvz[rl] = 1.0f / zsum;

    f32x4 acc[8];
#pragma unroll
    for (int s = 0; s < 8; ++s) acc[s] = (f32x4){0.f, 0.f, 0.f, 0.f};

    const float* seqb = seq + (size_t)b * 512 * 768 + nb;
    int tl = t & 31, jp = t >> 5;
    int n0 = tl * 4;
    auto stage = [&](int ch, int buf) {
        unsigned int* sb = sseq[buf];
#pragma unroll
        for (int pass = 0; pass < 4; ++pass) {
            int jl = pass * 16 + jp * 2;
            int jglob = ch * 64 + jl;
            float4 a0 = *(const float4*)(seqb + (size_t)jglob * 768 + n0);
            float4 a1 = *(const float4*)(seqb + (size_t)(jglob + 1) * 768 + n0);
            float a0v[4] = {a0.x, a0.y, a0.z, a0.w};
            float a1v[4] = {a1.x, a1.y, a1.z, a1.w};
            int g = jl >> 3;
            int wo = (jl & 7) >> 1;
#pragma unroll
            for (int i = 0; i < 4; ++i) {
                int n = n0 + i;
                int sw = (n ^ (n >> 3)) & 7;
                unsigned int pk = (unsigned int)f32_to_bf16(a0v[i]) |
                                  ((unsigned int)f32_to_bf16(a1v[i]) << 16);
                sb[n * 32 + ((g ^ sw) << 2) + wo] = pk;
            }
        }
    };

    __syncthreads();
    stage(0, 0);
    __syncthreads();
#pragma unroll
    for (int ch = 0; ch < 8; ++ch) {
        if (ch < 7) stage(ch + 1, (ch + 1) & 1);
        const unsigned int* cb = sseq[ch & 1];
#pragma unroll
        for (int kk = 0; kk < 2; ++kk) {
            short8 bfr[8];
#pragma unroll
            for (int s = 0; s < 8; ++s) {
                int n = s * 16 + mm;
                int g = kk * 4 + q;
                int sw = (n ^ (n >> 3)) & 7;
                bfr[s] = *(const short8*)(cb + n * 32 + ((g ^ sw) << 2));
            }
#pragma unroll
            for (int s = 0; s < 8; ++s)
                acc[s] = __builtin_amdgcn_mfma_f32_16x16x32_bf16(
                    afrag[ch * 2 + kk], bfr[s], acc[s], 0, 0, 0);
        }
        __syncthreads();
    }

    const float invsqrtk = 0.036084391824351615f;
#pragma unroll
    for (int reg = 0; reg < 4; ++reg) {
        int row = q * 4 + reg;
        int rr = rt * 64 + wv * 16 + row;
        if (rr < 196) {
            float scale = sinvz[wv * 16 + row] * invsqrtk;
            float* op = out + (size_t)(b * 196 + rr) * 768 + nb + mm;
#pragma unroll
            for (int s = 0; s < 8; ++s)
                op[s * 16] = acc[s][reg] * scale;
        }
    }
}

extern "C" void kernel_launch(void* const* d_in, const int* in_sizes, int n_in,
                              void* d_out, int out_size, void* d_ws, size_t ws_size,
                              hipStream_t stream) {
    const float* image_emb = (const float*)d_in[0];
    const float* seq_emb   = (const float*)d_in[1];
    const int*   mask      = (const int*)d_in[2];
    const float* image_W   = (const float*)d_in[3];
    const float* image_b   = (const float*)d_in[4];
    const float* seq_W     = (const float*)d_in[5];
    const float* seq_b     = (const float*)d_in[6];
    const float* V         = (const float*)d_in[7];
    float* out = (float*)d_out;

    float* p_ws  = (float*)d_ws;                              // 12544 f
    float* qpart = (float*)((char*)d_ws + (128 << 10));       // 6*64*512 f = 768 KB
    float* wm_ws = (float*)((char*)d_ws + (896 << 10));       // 32768 f = 128 KB
    unsigned short* seqT = (unsigned short*)((char*)d_ws + (1024 << 10));  // 64*768*512 bf16

    size_t need = (size_t)(1024 << 10) + (size_t)64 * 768 * 512 * 2;
    if (ws_size >= need) {
        kprep<<<dim3(6208), dim3(256), 0, stream>>>(seq_emb, seq_W,
                                                    image_emb, image_W, image_b,
                                                    seqT, qpart, p_ws);
        kw<<<dim3(512), dim3(256), 0, stream>>>(qpart, seq_b, V, mask, wm_ws, 6);
        kattn2<<<dim3(1536), dim3(256), 0, stream>>>(seqT, p_ws, wm_ws, out);
    } else {
        krows_p<<<dim3(3136), dim3(256), 0, stream>>>(image_emb, image_W, image_b, p_ws);
        krows_q<<<dim3(8192), dim3(256), 0, stream>>>(seq_emb, seq_W, qpart);
        kw<<<dim3(512), dim3(256), 0, stream>>>(qpart, seq_b, V, mask, wm_ws, 1);
        kattn<<<dim3(1536), dim3(256), 0, stream>>>(seq_emb, p_ws, wm_ws, out);
    }
}